// Round 3
// baseline (204.387 us; speedup 1.0000x reference)
//
#include <hip/hip_runtime.h>
#include <hip/hip_bf16.h>

typedef unsigned int u32;
typedef unsigned long long u64;

#define HH 384
#define WW 768
#define HW (HH*WW)
#define H4 96
#define W4 192
#define DLR 32
#define DHR 128
#define TOPK 8000
#define NTH 256
#define NBLK (HW/NTH)   // 1152

struct SelState {
    u32 K, all_pass, prefix, r, cutoff, n_take;
    u32 hist[256];
};

__global__ void k_init(SelState* st){
    int t = threadIdx.x;
    st->hist[t] = 0;
    if (t == 0){ st->K=0; st->all_pass=0; st->prefix=0; st->r=TOPK; st->cutoff=0; st->n_take=0; }
}

// ---- interp + per-pixel prob stats + confidence ----
__global__ __launch_bounds__(NTH) void k_prob(const float* __restrict__ P,
        const float* __restrict__ edge, const float* __restrict__ occ,
        float* __restrict__ conf, float* __restrict__ disp0, u32* __restrict__ dhk){
    int idx = blockIdx.x*NTH + threadIdx.x;
    int y = idx / WW, x = idx % WW;
    const float CY = (float)(95.0/383.0);
    const float CX = (float)(191.0/767.0);
    const float CD = (float)(31.0/127.0);
    float fy = (float)y * CY;
    int y0 = (int)fy; if (y0 > H4-1) y0 = H4-1;
    int y1 = min(y0+1, H4-1);
    float wy = fy - (float)y0;
    float fx = (float)x * CX;
    int x0 = (int)fx; if (x0 > W4-1) x0 = W4-1;
    int x1 = min(x0+1, W4-1);
    float wx = fx - (float)x0;

    const float* p00 = P + y0*W4 + x0;
    int o01 = x1 - x0, o10 = (y1 - y0)*W4, o11 = o10 + o01;

    float S[DLR];
    #pragma unroll
    for (int dl = 0; dl < DLR; ++dl){
        const float* p = p00 + dl*(H4*W4);
        float a = p[0], b = p[o01], c = p[o10], d = p[o11];
        float l = a*(1.0f-wy) + c*wy;
        float r = b*(1.0f-wy) + d*wy;
        S[dl] = l*(1.0f-wx) + r*wx;
    }

    float sum = 0.f, sumd = 0.f, vmax = -1.f, v2 = -1.f;
    int dmax = 0;
    #pragma unroll
    for (int d = 0; d < DHR; ++d){
        float pos = (float)d * CD;
        int lo = (int)pos; if (lo > DLR-1) lo = DLR-1;
        int hi = min(lo+1, DLR-1);
        float w = pos - (float)lo;
        float v = S[lo]*(1.0f-w) + S[hi]*w;
        sum  += v;
        sumd += (float)d * v;
        if (v > vmax){ v2 = vmax; vmax = v; dmax = d; }
        else if (v > v2) v2 = v;
    }
    float inv  = 1.0f/(sum + 1e-6f);
    float pmax = vmax*inv, p2 = v2*inv;
    float psr  = pmax/(p2 + 1e-6f);
    float cf   = pmax * tanhf(psr);
    cf *= expf(-2.0f*edge[idx]) * fmaxf(1.0f - occ[idx], 0.0f);
    conf[idx]  = cf;
    disp0[idx] = sumd*inv;
    dhk[idx]   = (u32)dmax;
}

// ---- 3x3 NMS + edge weights + anchor count ----
__global__ __launch_bounds__(NTH) void k_nms(const float* __restrict__ conf,
        const float* __restrict__ edge, const float* __restrict__ occ,
        u32* __restrict__ dhk, float* __restrict__ w1, float* __restrict__ w2,
        float* __restrict__ w3, float* __restrict__ w4, float* __restrict__ wsum,
        SelState* st){
    int idx = blockIdx.x*NTH + threadIdx.x;
    int y = idx / WW, x = idx % WW;
    float c = conf[idx];
    float pool = -1e30f;
    #pragma unroll
    for (int dy=-1; dy<=1; ++dy){
        int yy = y+dy; if (yy < 0 || yy >= HH) continue;
        #pragma unroll
        for (int dx=-1; dx<=1; ++dx){
            int xx = x+dx; if (xx < 0 || xx >= WW) continue;
            pool = fmaxf(pool, conf[yy*WW+xx]);
        }
    }
    bool keep = (c >= 0.1f) && (c >= pool);
    dhk[idx] |= keep ? 256u : 0u;

    int yu = min(y+1,HH-1), yd = max(y-1,0), xr = min(x+1,WW-1), xl = max(x-1,0);
    float e  = edge[idx],      o  = occ[idx];
    float e1 = edge[yu*WW+x],  o1 = occ[yu*WW+x];
    float e2 = edge[yd*WW+x],  o2 = occ[yd*WW+x];
    float e3 = edge[y*WW+xr],  o3 = occ[y*WW+xr];
    float e4 = edge[y*WW+xl],  o4 = occ[y*WW+xl];
    float a1 = expf(-(e+e1))*(1.f-o)*(1.f-o1);
    float a2 = expf(-(e+e2))*(1.f-o)*(1.f-o2);
    float a3 = expf(-(e+e3))*(1.f-o)*(1.f-o3);
    float a4 = expf(-(e+e4))*(1.f-o)*(1.f-o4);
    w1[idx]=a1; w2[idx]=a2; w3[idx]=a3; w4[idx]=a4;
    wsum[idx]= a1+a2+a3+a4+1e-6f;

    u64 m = __ballot(keep);
    __shared__ u32 wc[4];
    int lane = threadIdx.x & 63, wid = threadIdx.x >> 6;
    if (lane == 0) wc[wid] = (u32)__popcll(m);
    __syncthreads();
    if (threadIdx.x == 0) atomicAdd(&st->K, wc[0]+wc[1]+wc[2]+wc[3]);
}

// ---- radix-select histogram pass ----
__global__ __launch_bounds__(NTH) void k_hist(const float* __restrict__ conf,
        const u32* __restrict__ dhk, SelState* st, int pass){
    __shared__ u32 h[256];
    h[threadIdx.x] = 0;
    __syncthreads();
    bool skip = (pass > 0) && (st->all_pass != 0);
    if (!skip){
        int idx = blockIdx.x*NTH + threadIdx.x;
        u32 dv = dhk[idx];
        if (dv & 256u){
            u32 key = __float_as_uint(conf[idx]);
            bool match = true;
            if (pass > 0){
                int hb = 8*pass;
                match = (key >> (32-hb)) == (st->prefix >> (32-hb));
            }
            if (match) atomicAdd(&h[(key >> (24-8*pass)) & 255u], 1u);
        }
    }
    __syncthreads();
    if (h[threadIdx.x]) atomicAdd(&st->hist[threadIdx.x], h[threadIdx.x]);
}

// ---- radix-select advance (1 block) ----
__global__ void k_adv(SelState* st, int pass){
    __shared__ u32 h[256];
    int t = threadIdx.x;
    if (pass == 0 && t == 0){
        if (st->K <= TOPK) st->all_pass = 1;
    }
    __syncthreads();
    if (st->all_pass) return;
    h[t] = st->hist[t];
    st->hist[t] = 0;
    __syncthreads();
    if (t == 0){
        u32 r = st->r, c = 0; int dgt = 0;
        for (int d = 255; d >= 0; --d){
            if (r <= c + h[d]){ dgt = d; break; }
            c += h[d];
        }
        st->r = r - c;
        st->prefix |= ((u32)dgt) << (24-8*pass);
        if (pass == 3){ st->cutoff = st->prefix; st->n_take = r - c; }
    }
}

// ---- per-block count of cutoff-equal anchors ----
__global__ __launch_bounds__(NTH) void k_eqcnt(const float* __restrict__ conf,
        const u32* __restrict__ dhk, const SelState* st, u32* __restrict__ blk_cnt){
    int idx = blockIdx.x*NTH + threadIdx.x;
    bool flag = false;
    if (!st->all_pass){
        u32 dv = dhk[idx];
        if (dv & 256u) flag = (__float_as_uint(conf[idx]) == st->cutoff);
    }
    u64 m = __ballot(flag);
    __shared__ u32 wc[4];
    if ((threadIdx.x & 63) == 0) wc[threadIdx.x >> 6] = (u32)__popcll(m);
    __syncthreads();
    if (threadIdx.x == 0) blk_cnt[blockIdx.x] = wc[0]+wc[1]+wc[2]+wc[3];
}

// ---- exclusive scan of block counts (1 block, 256 threads, 5 each) ----
__global__ void k_scan(const u32* __restrict__ blk_cnt, u32* __restrict__ blk_off){
    __shared__ u32 s[256];
    int t = threadIdx.x;
    u32 v[5]; u32 loc = 0;
    #pragma unroll
    for (int i = 0; i < 5; ++i){
        int j = t*5 + i;
        u32 c = (j < NBLK) ? blk_cnt[j] : 0;
        v[i] = loc; loc += c;
    }
    s[t] = loc;
    __syncthreads();
    for (int off = 1; off < 256; off <<= 1){
        u32 x = (t >= off) ? s[t-off] : 0;
        __syncthreads();
        s[t] += x;
        __syncthreads();
    }
    u32 base = (t > 0) ? s[t-1] : 0;
    #pragma unroll
    for (int i = 0; i < 5; ++i){
        int j = t*5 + i;
        if (j < NBLK) blk_off[j] = base + v[i];
    }
}

// ---- final anchor selection + num0/denom + Jacobi iteration #1 ----
__global__ __launch_bounds__(NTH) void k_finalmaps(const float* __restrict__ conf,
        const float* __restrict__ disp0, const u32* __restrict__ dhk,
        const float* __restrict__ wsum, const SelState* st, const u32* __restrict__ blk_off,
        float* __restrict__ num0, float* __restrict__ denom, float* __restrict__ Ra){
    int idx = blockIdx.x*NTH + threadIdx.x;
    u32 dv = dhk[idx];
    bool keep = (dv & 256u) != 0;
    float c = conf[idx];
    u32 key = __float_as_uint(c);
    bool ap = st->all_pass != 0;
    u32 cut = st->cutoff;
    bool eq = keep && !ap && (key == cut);

    u64 m = __ballot(eq);
    __shared__ u32 wc[4];
    int lane = threadIdx.x & 63, wid = threadIdx.x >> 6;
    if (lane == 0) wc[wid] = (u32)__popcll(m);
    __syncthreads();
    u32 before = (u32)__popcll(m & ((lane == 0) ? 0ull : ((1ull << lane) - 1ull)));
    for (int w = 0; w < wid; ++w) before += wc[w];

    bool kf;
    if (!keep) kf = false;
    else if (ap) kf = true;
    else if (key > cut) kf = true;
    else if (eq) kf = (blk_off[blockIdx.x] + before) < st->n_take;
    else kf = false;

    float mm = kf ? fminf(fmaxf(c, 0.0f), 1.0f) : 0.0f;
    float n0 = mm * ((float)(dv & 255u) - disp0[idx]);
    float den = mm + 0.8f*wsum[idx] + 1e-6f;
    num0[idx] = n0;
    denom[idx] = den;
    Ra[idx] = n0 / den;    // iteration 1 (R_prev = 0)
}

// ---- Jacobi iteration (+ fused final clip) ----
__global__ __launch_bounds__(NTH) void k_jacobi(const float* __restrict__ Rin,
        float* __restrict__ Rout, const float* __restrict__ num0,
        const float* __restrict__ denom, const float* __restrict__ w1,
        const float* __restrict__ w2, const float* __restrict__ w3,
        const float* __restrict__ w4, const float* __restrict__ disp0,
        float* __restrict__ out, int final_it){
    int idx = blockIdx.x*NTH + threadIdx.x;
    int y = idx / WW, x = idx % WW;
    int yu = min(y+1,HH-1), yd = max(y-1,0), xr = min(x+1,WW-1), xl = max(x-1,0);
    float nbr = w1[idx]*Rin[yu*WW+x] + w2[idx]*Rin[yd*WW+x]
              + w3[idx]*Rin[y*WW+xr] + w4[idx]*Rin[y*WW+xl];
    float Rn = (num0[idx] + 0.8f*nbr) / denom[idx];
    if (final_it) out[idx] = fmaxf(disp0[idx] + Rn, 0.0f);
    else Rout[idx] = Rn;
}

extern "C" void kernel_launch(void* const* d_in, const int* in_sizes, int n_in,
                              void* d_out, int out_size, void* d_ws, size_t ws_size,
                              hipStream_t stream) {
    const float* P    = (const float*)d_in[0];
    const float* edge = (const float*)d_in[1];
    const float* occ  = (const float*)d_in[2];
    float* out = (float*)d_out;

    float* conf  = (float*)d_ws;
    float* disp0 = conf  + HW;
    u32*   dhk   = (u32*)(disp0 + HW);
    float* w1    = (float*)(dhk + HW);
    float* w2    = w1 + HW;
    float* w3    = w2 + HW;
    float* w4    = w3 + HW;
    float* wsum  = w4 + HW;
    float* num0  = wsum + HW;
    float* denom = num0 + HW;
    float* Ra    = denom + HW;
    float* Rb    = Ra + HW;
    u32* blk_cnt = (u32*)(Rb + HW);
    u32* blk_off = blk_cnt + NBLK;
    SelState* st = (SelState*)(blk_off + NBLK);

    dim3 grid(NBLK), block(NTH);
    k_init<<<1, 256, 0, stream>>>(st);
    k_prob<<<grid, block, 0, stream>>>(P, edge, occ, conf, disp0, dhk);
    k_nms<<<grid, block, 0, stream>>>(conf, edge, occ, dhk, w1, w2, w3, w4, wsum, st);
    for (int p = 0; p < 4; ++p){
        k_hist<<<grid, block, 0, stream>>>(conf, dhk, st, p);
        k_adv<<<1, 256, 0, stream>>>(st, p);
    }
    k_eqcnt<<<grid, block, 0, stream>>>(conf, dhk, st, blk_cnt);
    k_scan<<<1, 256, 0, stream>>>(blk_cnt, blk_off);
    k_finalmaps<<<grid, block, 0, stream>>>(conf, disp0, dhk, wsum, st, blk_off,
                                            num0, denom, Ra);
    float* ra = Ra; float* rb = Rb;
    for (int it = 2; it <= 30; ++it){
        k_jacobi<<<grid, block, 0, stream>>>(ra, rb, num0, denom, w1, w2, w3, w4,
                                             disp0, out, (it == 30) ? 1 : 0);
        float* tmp = ra; ra = rb; rb = tmp;
    }
}

// Round 6
// 180.234 us; speedup vs baseline: 1.1340x; 1.1340x over previous
//
#include <hip/hip_runtime.h>
#include <hip/hip_bf16.h>

typedef unsigned int u32;
typedef unsigned long long u64;

#define HH 384
#define WW 768
#define HW (HH*WW)
#define H4 96
#define W4 192
#define DLR 32
#define DHR 128
#define TOPK 8000
#define NTH 256
#define NBLK (HW/NTH)   // 1152

// k_prob tiling: 4 rows x 64 cols per block
#define PTW 18
#define PTH 3

// jacobi halo tiling: 16x48 interior, 32x64 staged region
#define JRH 32
#define JRW 64
#define JRN (JRH*JRW)    // 2048
#define JTILW 48
#define JTILH 16
#define JGX 16           // 768/48
#define JGY 24           // 384/16

struct SelState {
    u32 K, all_pass, prefix, r, cutoff, n_take;
};

__global__ void k_init(SelState* st){
    if (threadIdx.x == 0){
        st->K = 0; st->all_pass = 0; st->prefix = 0;
        st->r = TOPK; st->cutoff = 0; st->n_take = 0;
    }
}

// ---- interp + per-pixel prob stats + confidence (LDS-staged) ----
__global__ __launch_bounds__(NTH) void k_prob(const float* __restrict__ P,
        const float* __restrict__ edge, const float* __restrict__ occ,
        float* __restrict__ conf, float* __restrict__ disp0, u32* __restrict__ dhk){
    __shared__ float Sl[DLR][PTH][PTW];   // 6912 B
    int bx = blockIdx.x % 12;             // 12 x-tiles of 64
    int by = blockIdx.x / 12;             // 96 y-tiles of 4
    int lx = threadIdx.x & 63, ly = threadIdx.x >> 6;
    int X = bx*64, Y = by*4;

    const float CY = (float)(95.0/383.0);
    const float CX = (float)(191.0/767.0);
    const float CD = (float)(31.0/127.0);

    float fy0 = (float)Y * CY; int y0min = (int)fy0; if (y0min > H4-1) y0min = H4-1;
    float fx0 = (float)X * CX; int x0min = (int)fx0; if (x0min > W4-1) x0min = W4-1;

    // stage P_lr window: 32 planes x 3 rows x 18 cols, replicate-clamped
    for (int e = threadIdx.x; e < DLR*PTH*PTW; e += NTH){
        int dl  = e / (PTH*PTW);
        int rem = e % (PTH*PTW);
        int ry  = rem / PTW;
        int cx  = rem % PTW;
        int gy = min(y0min + ry, H4-1);
        int gx = min(x0min + cx, W4-1);
        ((float*)Sl)[e] = P[dl*(H4*W4) + gy*W4 + gx];
    }
    __syncthreads();

    int x = X + lx, y = Y + ly;
    int idx = y*WW + x;

    float fy = (float)y * CY;
    int y0 = (int)fy; if (y0 > H4-1) y0 = H4-1;
    int y1 = min(y0+1, H4-1);
    float wy = fy - (float)y0;
    float fx = (float)x * CX;
    int x0 = (int)fx; if (x0 > W4-1) x0 = W4-1;
    int x1 = min(x0+1, W4-1);
    float wx = fx - (float)x0;

    int ry  = y0 - y0min;   // 0..1
    int ryb = y1 - y0min;   // <= 2
    int cx  = x0 - x0min;   // 0..16
    int cxb = x1 - x0min;   // <= 17

    float S[DLR];
    #pragma unroll
    for (int dl = 0; dl < DLR; ++dl){
        float a = Sl[dl][ry][cx],  b = Sl[dl][ry][cxb];
        float c = Sl[dl][ryb][cx], d = Sl[dl][ryb][cxb];
        float l = a*(1.0f-wy) + c*wy;
        float r = b*(1.0f-wy) + d*wy;
        S[dl] = l*(1.0f-wx) + r*wx;
    }

    float sum = 0.f, sumd = 0.f, vmax = -1.f, v2 = -1.f;
    int dmax = 0;
    #pragma unroll
    for (int d = 0; d < DHR; ++d){
        float pos = (float)d * CD;
        int lo = (int)pos; if (lo > DLR-1) lo = DLR-1;
        int hi = min(lo+1, DLR-1);
        float w = pos - (float)lo;
        float v = S[lo]*(1.0f-w) + S[hi]*w;
        sum  += v;
        sumd += (float)d * v;
        if (v > vmax){ v2 = vmax; vmax = v; dmax = d; }
        else if (v > v2) v2 = v;
    }
    float inv  = 1.0f/(sum + 1e-6f);
    float pmax = vmax*inv, p2 = v2*inv;
    float psr  = pmax/(p2 + 1e-6f);
    float cf   = pmax * tanhf(psr);
    cf *= expf(-2.0f*edge[idx]) * fmaxf(1.0f - occ[idx], 0.0f);
    conf[idx]  = cf;
    disp0[idx] = sumd*inv;
    dhk[idx]   = (u32)dmax;
}

// ---- 3x3 NMS + edge weights (float4) + anchor count + hi16 histogram ----
__global__ __launch_bounds__(NTH) void k_nms(const float* __restrict__ conf,
        const float* __restrict__ edge, const float* __restrict__ occ,
        u32* __restrict__ dhk, float4* __restrict__ w4pack,
        u32* __restrict__ hist_hi, SelState* st){
    int idx = blockIdx.x*NTH + threadIdx.x;
    int y = idx / WW, x = idx % WW;
    float c = conf[idx];
    float pool = -1e30f;
    #pragma unroll
    for (int dy=-1; dy<=1; ++dy){
        int yy = y+dy; if (yy < 0 || yy >= HH) continue;
        #pragma unroll
        for (int dx=-1; dx<=1; ++dx){
            int xx = x+dx; if (xx < 0 || xx >= WW) continue;
            pool = fmaxf(pool, conf[yy*WW+xx]);
        }
    }
    bool keep = (c >= 0.1f) && (c >= pool);
    dhk[idx] |= keep ? 256u : 0u;

    int yu = min(y+1,HH-1), yd = max(y-1,0), xr = min(x+1,WW-1), xl = max(x-1,0);
    float e  = edge[idx],      o  = occ[idx];
    float e1 = edge[yu*WW+x],  o1 = occ[yu*WW+x];
    float e2 = edge[yd*WW+x],  o2 = occ[yd*WW+x];
    float e3 = edge[y*WW+xr],  o3 = occ[y*WW+xr];
    float e4 = edge[y*WW+xl],  o4 = occ[y*WW+xl];
    float4 wp;
    wp.x = expf(-(e+e1))*(1.f-o)*(1.f-o1);
    wp.y = expf(-(e+e2))*(1.f-o)*(1.f-o2);
    wp.z = expf(-(e+e3))*(1.f-o)*(1.f-o3);
    wp.w = expf(-(e+e4))*(1.f-o)*(1.f-o4);
    w4pack[idx] = wp;

    if (keep) atomicAdd(&hist_hi[__float_as_uint(c) >> 16], 1u);

    u64 m = __ballot(keep);
    __shared__ u32 wc[4];
    int lane = threadIdx.x & 63, wid = threadIdx.x >> 6;
    if (lane == 0) wc[wid] = (u32)__popcll(m);
    __syncthreads();
    if (threadIdx.x == 0) atomicAdd(&st->K, wc[0]+wc[1]+wc[2]+wc[3]);
}

// ---- hi16 select (1 block) ----
__global__ void k_advhi(const u32* __restrict__ hist, SelState* st){
    __shared__ u32 csum[256];
    int t = threadIdx.x;
    u32 s = 0;
    for (int i = 0; i < 256; ++i) s += hist[t*256 + i];
    csum[t] = s;
    __syncthreads();
    if (t == 0){
        if (st->K <= TOPK){ st->all_pass = 1; }
        else {
            u32 r = TOPK, suf = 0; int tb = 0;
            for (int u = 255; u >= 0; --u){
                if (r <= suf + csum[u]){ tb = u; break; }
                suf += csum[u];
            }
            u32 c = suf;
            for (int i = 255; i >= 0; --i){
                u32 h = hist[tb*256 + i];
                if (r <= c + h){ st->prefix = (u32)(tb*256 + i); st->r = r - c; break; }
                c += h;
            }
        }
    }
}

// ---- lo16 histogram over matching hi bucket ----
__global__ __launch_bounds__(NTH) void k_histlo(const float* __restrict__ conf,
        const u32* __restrict__ dhk, const SelState* st, u32* __restrict__ hist_lo){
    if (st->all_pass) return;
    int idx = blockIdx.x*NTH + threadIdx.x;
    u32 dv = dhk[idx];
    if (dv & 256u){
        u32 key = __float_as_uint(conf[idx]);
        if ((key >> 16) == st->prefix) atomicAdd(&hist_lo[key & 0xffffu], 1u);
    }
}

// ---- lo16 select (1 block) ----
__global__ void k_advlo(const u32* __restrict__ hist, SelState* st){
    __shared__ u32 csum[256];
    int t = threadIdx.x;
    u32 s = 0;
    for (int i = 0; i < 256; ++i) s += hist[t*256 + i];
    csum[t] = s;
    __syncthreads();
    if (t == 0 && !st->all_pass){
        u32 r = st->r, suf = 0; int tb = 0;
        for (int u = 255; u >= 0; --u){
            if (r <= suf + csum[u]){ tb = u; break; }
            suf += csum[u];
        }
        u32 c = suf;
        for (int i = 255; i >= 0; --i){
            u32 h = hist[tb*256 + i];
            if (r <= c + h){
                st->cutoff = (st->prefix << 16) | (u32)(tb*256 + i);
                st->n_take = r - c;
                break;
            }
            c += h;
        }
    }
}

// ---- per-block count of cutoff-equal anchors ----
__global__ __launch_bounds__(NTH) void k_eqcnt(const float* __restrict__ conf,
        const u32* __restrict__ dhk, const SelState* st, u32* __restrict__ blk_cnt){
    int idx = blockIdx.x*NTH + threadIdx.x;
    bool flag = false;
    if (!st->all_pass){
        u32 dv = dhk[idx];
        if (dv & 256u) flag = (__float_as_uint(conf[idx]) == st->cutoff);
    }
    u64 m = __ballot(flag);
    __shared__ u32 wc[4];
    if ((threadIdx.x & 63) == 0) wc[threadIdx.x >> 6] = (u32)__popcll(m);
    __syncthreads();
    if (threadIdx.x == 0) blk_cnt[blockIdx.x] = wc[0]+wc[1]+wc[2]+wc[3];
}

// ---- exclusive scan of block counts (1 block) ----
__global__ void k_scan(const u32* __restrict__ blk_cnt, u32* __restrict__ blk_off){
    __shared__ u32 s[256];
    int t = threadIdx.x;
    u32 v[5]; u32 loc = 0;
    #pragma unroll
    for (int i = 0; i < 5; ++i){
        int j = t*5 + i;
        u32 c = (j < NBLK) ? blk_cnt[j] : 0;
        v[i] = loc; loc += c;
    }
    s[t] = loc;
    __syncthreads();
    for (int off = 1; off < 256; off <<= 1){
        u32 x = (t >= off) ? s[t-off] : 0;
        __syncthreads();
        s[t] += x;
        __syncthreads();
    }
    u32 base = (t > 0) ? s[t-1] : 0;
    #pragma unroll
    for (int i = 0; i < 5; ++i){
        int j = t*5 + i;
        if (j < NBLK) blk_off[j] = base + v[i];
    }
}

// ---- final selection + nhat/what + Jacobi iter #1 ----
__global__ __launch_bounds__(NTH) void k_finalmaps(const float* __restrict__ conf,
        const float* __restrict__ disp0, const u32* __restrict__ dhk,
        const SelState* st, const u32* __restrict__ blk_off,
        float4* __restrict__ w4pack, float* __restrict__ nhat, float* __restrict__ Ra){
    int idx = blockIdx.x*NTH + threadIdx.x;
    u32 dv = dhk[idx];
    bool keep = (dv & 256u) != 0;
    float c = conf[idx];
    u32 key = __float_as_uint(c);
    bool ap = st->all_pass != 0;
    u32 cut = st->cutoff;
    bool eq = keep && !ap && (key == cut);

    u64 m = __ballot(eq);
    __shared__ u32 wc[4];
    int lane = threadIdx.x & 63, wid = threadIdx.x >> 6;
    if (lane == 0) wc[wid] = (u32)__popcll(m);
    __syncthreads();
    u32 before = (u32)__popcll(m & ((lane == 0) ? 0ull : ((1ull << lane) - 1ull)));
    for (int w = 0; w < wid; ++w) before += wc[w];

    bool kf;
    if (!keep) kf = false;
    else if (ap) kf = true;
    else if (key > cut) kf = true;
    else if (eq) kf = (blk_off[blockIdx.x] + before) < st->n_take;
    else kf = false;

    float mm = kf ? fminf(fmaxf(c, 0.0f), 1.0f) : 0.0f;
    float4 wp = w4pack[idx];
    float wsum = wp.x + wp.y + wp.z + wp.w + 1e-6f;
    float den = mm + 0.8f*wsum + 1e-6f;
    float n0 = mm * ((float)(dv & 255u) - disp0[idx]);
    float nh = n0 / den;
    float sc = 0.8f / den;
    wp.x *= sc; wp.y *= sc; wp.z *= sc; wp.w *= sc;
    w4pack[idx] = wp;
    nhat[idx] = nh;
    Ra[idx] = nh;   // iteration 1 (R_prev = 0)
}

// ---- K Jacobi iterations in LDS with halo (+ fused final clip) ----
__global__ __launch_bounds__(NTH) void k_jac(const float* __restrict__ Rin,
        float* __restrict__ Rout, const float4* __restrict__ Wp,
        const float* __restrict__ Nh, const float* __restrict__ disp0,
        float* __restrict__ out, int K, int final_it){
    __shared__ float4 Wv[JRN];       // 32 KB
    __shared__ float  Nv[JRN];       // 8 KB
    __shared__ float  Rb[2][JRN];    // 16 KB
    int bx = blockIdx.x % JGX, by = blockIdx.x / JGX;
    int ry0 = by*JTILH - 8, cx0 = bx*JTILW - 8;

    for (int e = threadIdx.x; e < JRN; e += NTH){
        int r = e / JRW, c = e % JRW;
        int gy = min(max(ry0 + r, 0), HH-1);
        int gx = min(max(cx0 + c, 0), WW-1);
        int g = gy*WW + gx;
        Wv[e] = Wp[g];
        Nv[e] = Nh[g];
        Rb[0][e] = Rin[g];
    }
    __syncthreads();

    int cur = 0;
    for (int j = 1; j <= K; ++j){
        int h = JRH - 2*j, w = JRW - 2*j, tot = h*w;
        for (int p = threadIdx.x; p < tot; p += NTH){
            int r = j + p / w, c = j + p % w;
            int gy = ry0 + r, gx = cx0 + c;
            if ((u32)gy < (u32)HH && (u32)gx < (u32)WW){
                int base = r*JRW + c;
                int up = (gy > 0)    ? base - JRW : base;
                int dn = (gy < HH-1) ? base + JRW : base;
                int lf = (gx > 0)    ? base - 1   : base;
                int rt = (gx < WW-1) ? base + 1   : base;
                float4 wv = Wv[base];
                Rb[cur^1][base] = Nv[base] + wv.x*Rb[cur][up] + wv.y*Rb[cur][dn]
                                + wv.z*Rb[cur][lf] + wv.w*Rb[cur][rt];
            }
        }
        __syncthreads();
        cur ^= 1;
    }

    for (int p = threadIdx.x; p < JTILH*JTILW; p += NTH){
        int r = 8 + p / JTILW, c = 8 + p % JTILW;
        int gy = ry0 + r, gx = cx0 + c;
        int g = gy*WW + gx;
        float Rv = Rb[cur][r*JRW + c];
        if (final_it) out[g] = fmaxf(disp0[g] + Rv, 0.0f);
        else Rout[g] = Rv;
    }
}

extern "C" void kernel_launch(void* const* d_in, const int* in_sizes, int n_in,
                              void* d_out, int out_size, void* d_ws, size_t ws_size,
                              hipStream_t stream) {
    const float* P    = (const float*)d_in[0];
    const float* edge = (const float*)d_in[1];
    const float* occ  = (const float*)d_in[2];
    float* out = (float*)d_out;

    float*  conf   = (float*)d_ws;
    float*  disp0  = conf + HW;
    u32*    dhk    = (u32*)(disp0 + HW);
    float4* w4pack = (float4*)(dhk + HW);        // 4*HW floats, 16B-aligned
    float*  nhat   = (float*)(w4pack + HW);
    float*  Ra     = nhat + HW;
    float*  Rb     = Ra + HW;
    u32*    hist   = (u32*)(Rb + HW);            // hist_hi[65536] + hist_lo[65536]
    u32*    hist_hi = hist;
    u32*    hist_lo = hist + 65536;
    u32*    blk_cnt = hist_lo + 65536;
    u32*    blk_off = blk_cnt + NBLK;
    SelState* st   = (SelState*)(blk_off + NBLK);

    dim3 grid(NBLK), block(NTH);
    hipMemsetAsync(hist, 0, 2*65536*sizeof(u32), stream);
    k_init<<<1, 64, 0, stream>>>(st);
    k_prob<<<grid, block, 0, stream>>>(P, edge, occ, conf, disp0, dhk);
    k_nms<<<grid, block, 0, stream>>>(conf, edge, occ, dhk, w4pack, hist_hi, st);
    k_advhi<<<1, 256, 0, stream>>>(hist_hi, st);
    k_histlo<<<grid, block, 0, stream>>>(conf, dhk, st, hist_lo);
    k_advlo<<<1, 256, 0, stream>>>(hist_lo, st);
    k_eqcnt<<<grid, block, 0, stream>>>(conf, dhk, st, blk_cnt);
    k_scan<<<1, 256, 0, stream>>>(blk_cnt, blk_off);
    k_finalmaps<<<grid, block, 0, stream>>>(conf, disp0, dhk, st, blk_off,
                                            w4pack, nhat, Ra);
    // iterations 2..30 in 4 halo launches: 8+8+8+5
    dim3 jgrid(JGX*JGY);
    k_jac<<<jgrid, block, 0, stream>>>(Ra, Rb, w4pack, nhat, disp0, out, 8, 0);
    k_jac<<<jgrid, block, 0, stream>>>(Rb, Ra, w4pack, nhat, disp0, out, 8, 0);
    k_jac<<<jgrid, block, 0, stream>>>(Ra, Rb, w4pack, nhat, disp0, out, 8, 0);
    k_jac<<<jgrid, block, 0, stream>>>(Rb, Ra, w4pack, nhat, disp0, out, 5, 1);
}